// Round 1
// baseline (224.730 us; speedup 1.0000x reference)
//
#include <hip/hip_runtime.h>
#include <math.h>

// Problem: ProcessFeatures_83296595738632
// sat: (96,4,64,16) f32, grd: (96,4,64,16) f32
// corr[bs,bg,i] = sum_{h,j,k} sat[bs,h,(i+j)%64,k] * grd[bg,h,j,15-k]   (c-axis reversed!)
// orien[bs,bg]  = argmax_i corr  (first-max tie-break)
// dot[bs,bg]    = sum_{h,j,k} sat[bs,h,(j+orien)%64,k] * grd[bg,h,j,k] / ||sat[bs]||
// distance[bg,bs] = 2 - 2*dot[bs,bg]
// d_out (float32 flat): sat(393216) | grd(393216) | distance(9216) | orien(9216, as float values)

#define BS   96
#define H    4
#define W    64
#define C    16
#define BG   96
#define NB   8            // bg per block
#define PADW 20           // padded row stride (floats) for satL: bank-stride 20 -> conflict-free b128
#define NTH  256

#define SAT_ELEMS (BS*H*W*C)      // 393216
#define OUT_DIST  (2*SAT_ELEMS)   // 786432
#define OUT_ORIEN (OUT_DIST + BS*BG) // 795648

__global__ __launch_bounds__(NTH)
void pf_fused_kernel(const float* __restrict__ sat,
                     const float* __restrict__ grd,
                     float* __restrict__ out)
{
    __shared__ float satL[H * W * PADW];        // 20480 B
    __shared__ float grdL[NB * H * W * C];      // 131072 B
    __shared__ float partL[NB * W * 4];         // 8192 B
    __shared__ float sumL[4];
    __shared__ float dotP[NB * 4];
    __shared__ int   orienL[NB];

    const int bs   = blockIdx.y;
    const int bg0  = blockIdx.x * NB;
    const int tid  = threadIdx.x;
    const int wv   = tid >> 6;      // wave id == h slice
    const int lane = tid & 63;

    // ---- stage sat[bs] into LDS (padded rows) ----
    {
        const float* satB = sat + bs * (H*W*C);
        for (int x = tid; x < H*W*C; x += NTH) {
            int hw = x >> 4;        // h*64 + w
            int k  = x & 15;
            satL[hw * PADW + k] = satB[x];
        }
    }
    // ---- stage grd[bg0..bg0+7] into LDS (linear, float4) ----
    {
        const float4* g4 = (const float4*)(grd + (size_t)bg0 * (H*W*C));
        float4* l4 = (float4*)grdL;
        for (int x = tid; x < NB*H*W*C/4; x += NTH) l4[x] = g4[x];
    }
    __syncthreads();

    // ---- per-h squared sums for the norm ----
    {
        float s = 0.f;
        const float* r = &satL[(wv*W + lane) * PADW];
        #pragma unroll
        for (int k = 0; k < C; k += 4) {
            float4 v = *(const float4*)(r + k);
            s += v.x*v.x + v.y*v.y + v.z*v.z + v.w*v.w;
        }
        #pragma unroll
        for (int off = 32; off; off >>= 1) s += __shfl_xor(s, off);
        if (lane == 0) sumL[wv] = s;
    }

    // ---- corr: lane = shift i, wave = h, 8 bg accumulators ----
    float acc[NB];
    #pragma unroll
    for (int b = 0; b < NB; ++b) acc[b] = 0.f;

    for (int j = 0; j < W; ++j) {
        const float* satRow = &satL[(wv*W + ((lane + j) & 63)) * PADW];
        const float* grdRow = &grdL[(wv*W + j) * C];
        #pragma unroll
        for (int c4 = 0; c4 < 4; ++c4) {
            const int k0 = c4 * 4;
            float4 s4 = *(const float4*)(satRow + k0);
            #pragma unroll
            for (int b = 0; b < NB; ++b) {
                // c-axis reversed pairing: sat[k0+t] * grd[15-(k0+t)]
                float4 g4 = *(const float4*)(grdRow + b*(H*W*C) + (12 - k0));
                acc[b] += s4.x*g4.w + s4.y*g4.z + s4.z*g4.y + s4.w*g4.x;
            }
        }
    }

    #pragma unroll
    for (int b = 0; b < NB; ++b) partL[(b*W + lane)*4 + wv] = acc[b];
    __syncthreads();

    // ---- argmax per bg (first-max tie-break, numpy semantics) ----
    for (int b = wv; b < NB; b += 4) {
        float4 p = *(const float4*)&partL[(b*W + lane)*4];
        float v  = (p.x + p.y) + (p.z + p.w);
        int  idx = lane;
        #pragma unroll
        for (int off = 32; off; off >>= 1) {
            float ov = __shfl_xor(v, off);
            int   oi = __shfl_xor(idx, off);
            if (ov > v || (ov == v && oi < idx)) { v = ov; idx = oi; }
        }
        if (lane == 0) {
            orienL[b] = idx;
            out[OUT_ORIEN + bs*BG + (bg0 + b)] = (float)idx;  // int value as float
        }
    }
    __syncthreads();

    const float nrm = sqrtf(sumL[0] + sumL[1] + sumL[2] + sumL[3] + 1e-8f);

    // ---- dot phase: wave = h, lane = j ----
    {
        float dp[NB];
        #pragma unroll
        for (int b = 0; b < NB; ++b) {
            const int row = (lane + orienL[b]) & 63;
            const float* satRow = &satL[(wv*W + row) * PADW];
            const float* grdRow = &grdL[b*(H*W*C) + (wv*W + lane) * C];
            float s = 0.f;
            #pragma unroll
            for (int k0 = 0; k0 < C; k0 += 4) {
                float4 s4 = *(const float4*)(satRow + k0);
                float4 g4 = *(const float4*)(grdRow + k0);
                s += s4.x*g4.x + s4.y*g4.y + s4.z*g4.z + s4.w*g4.w;
            }
            dp[b] = s;
        }
        #pragma unroll
        for (int b = 0; b < NB; ++b) {
            float s = dp[b];
            #pragma unroll
            for (int off = 32; off; off >>= 1) s += __shfl_xor(s, off);
            if (lane == 0) dotP[b*4 + wv] = s;
        }
    }
    __syncthreads();

    if (tid < NB) {
        float d = ((dotP[tid*4+0] + dotP[tid*4+1]) + (dotP[tid*4+2] + dotP[tid*4+3])) / nrm;
        out[OUT_DIST + (size_t)(bg0 + tid)*BS + bs] = 2.f - 2.f*d;
    }
}

extern "C" void kernel_launch(void* const* d_in, const int* in_sizes, int n_in,
                              void* d_out, int out_size, void* d_ws, size_t ws_size,
                              hipStream_t stream) {
    const float* sat = (const float*)d_in[0];
    const float* grd = (const float*)d_in[1];
    float* out = (float*)d_out;

    // passthrough outputs 0 and 1
    hipMemcpyAsync(out,             sat, (size_t)SAT_ELEMS * sizeof(float),
                   hipMemcpyDeviceToDevice, stream);
    hipMemcpyAsync(out + SAT_ELEMS, grd, (size_t)SAT_ELEMS * sizeof(float),
                   hipMemcpyDeviceToDevice, stream);

    dim3 grid(BG / NB, BS);   // (12, 96)
    pf_fused_kernel<<<grid, NTH, 0, stream>>>(sat, grd, out);
}